// Round 1
// baseline (25.161 us; speedup 1.0000x reference)
//
#include <hip/hip_runtime.h>
#include <hip/hip_bf16.h>

// Pooler ragged-mean: out[b,s,:] = mean(features[b, begins[b,s]:ends[b,s], :])
// B=8, T=4096, D=256, S=1024, MAX_W=32. Empty spans -> 0.
//
// One 64-lane wave per span; each lane owns 4 channels (float4).
// 4 waves (spans) per 256-thread block -> 2048 blocks total.

#define B_DIM 8
#define T_DIM 4096
#define D_DIM 256
#define S_DIM 1024
#define MAX_W 32

__global__ __launch_bounds__(256) void pooler_kernel(
    const float* __restrict__ features,   // [B, T, D]
    const int*   __restrict__ begins,     // [B, S]
    const int*   __restrict__ ends,       // [B, S]
    float*       __restrict__ out)        // [B, S, D]
{
    const int span = blockIdx.x * 4 + (threadIdx.x >> 6);  // [0, B*S)
    const int lane = threadIdx.x & 63;

    const int b = span >> 10;  // S_DIM = 1024

    int begin = begins[span];
    int end   = ends[span];
    begin = begin > 0 ? begin : 0;
    end   = end   > 0 ? end   : 0;
    int w = end - begin;
    w = w > MAX_W ? MAX_W : w;
    w = w > 0 ? w : 0;

    const int c0 = lane * 4;  // channel offset for this lane

    float4 acc = make_float4(0.f, 0.f, 0.f, 0.f);
    const float* fb = features + (size_t)b * T_DIM * D_DIM;

    #pragma unroll 4
    for (int j = 0; j < w; ++j) {
        int row = begin + j;
        row = row < (T_DIM - 1) ? row : (T_DIM - 1);  // idx clip as in reference
        const float4 v = *reinterpret_cast<const float4*>(fb + (size_t)row * D_DIM + c0);
        acc.x += v.x; acc.y += v.y; acc.z += v.z; acc.w += v.w;
    }

    const float inv = 1.0f / (float)(w > 1 ? w : 1);
    float4 r = make_float4(acc.x * inv, acc.y * inv, acc.z * inv, acc.w * inv);
    *reinterpret_cast<float4*>(out + (size_t)span * D_DIM + c0) = r;
}

extern "C" void kernel_launch(void* const* d_in, const int* in_sizes, int n_in,
                              void* d_out, int out_size, void* d_ws, size_t ws_size,
                              hipStream_t stream) {
    const float* features = (const float*)d_in[0];
    const int*   begins   = (const int*)d_in[1];
    const int*   ends     = (const int*)d_in[2];
    float*       out      = (float*)d_out;

    const int n_spans = B_DIM * S_DIM;            // 8192
    const int blocks  = n_spans / 4;              // 4 spans (waves) per block
    pooler_kernel<<<blocks, 256, 0, stream>>>(features, begins, ends, out);
}

// Round 2
// 14.726 us; speedup vs baseline: 1.7087x; 1.7087x over previous
//
#include <hip/hip_runtime.h>
#include <hip/hip_bf16.h>

// Pooler ragged-mean: out[b,s,:] = mean(features[b, begins[b,s]:ends[b,s], :])
// B=8, T=4096, D=256, S=1024, MAX_W=32. Empty spans -> 0.
//
// One 64-lane wave per span; each lane owns 4 channels (float4).
// 4 waves (spans) per 256-thread block -> 2048 blocks total.
//
// XCD-aware swizzle: features is 4 MB per batch == one XCD's L2. Physical
// block i dispatches to XCD i%8 (round-robin); remap so XCD x handles
// exactly batch x -> each XCD's read set fits entirely in its own L2.

#define B_DIM 8
#define T_DIM 4096
#define D_DIM 256
#define S_DIM 1024
#define MAX_W 32
#define NXCD 8

__global__ __launch_bounds__(256) void pooler_kernel(
    const float* __restrict__ features,   // [B, T, D]
    const int*   __restrict__ begins,     // [B, S]
    const int*   __restrict__ ends,       // [B, S]
    float*       __restrict__ out)        // [B, S, D]
{
    // 2048 blocks, 256 blocks per batch. Physical block i -> XCD i%8.
    // logical block = (i%8)*256 + i/8  => XCD x gets logical blocks
    // [x*256, (x+1)*256) == all of batch x. Bijective for 2048 % 8 == 0.
    const int phys = blockIdx.x;
    const int lblk = (phys & (NXCD - 1)) * (2048 / NXCD) + (phys >> 3);

    const int span = lblk * 4 + (threadIdx.x >> 6);  // [0, B*S)
    const int lane = threadIdx.x & 63;

    const int b = span >> 10;  // S_DIM = 1024

    int begin = begins[span];
    int end   = ends[span];
    begin = begin > 0 ? begin : 0;
    end   = end   > 0 ? end   : 0;
    int w = end - begin;
    w = w > MAX_W ? MAX_W : w;
    w = w > 0 ? w : 0;

    const int c0 = lane * 4;  // channel offset for this lane

    float4 acc = make_float4(0.f, 0.f, 0.f, 0.f);
    const float* fb = features + (size_t)b * T_DIM * D_DIM;

    #pragma unroll 8
    for (int j = 0; j < w; ++j) {
        int row = begin + j;
        row = row < (T_DIM - 1) ? row : (T_DIM - 1);  // idx clip as in reference
        const float4 v = *reinterpret_cast<const float4*>(fb + (size_t)row * D_DIM + c0);
        acc.x += v.x; acc.y += v.y; acc.z += v.z; acc.w += v.w;
    }

    const float inv = 1.0f / (float)(w > 1 ? w : 1);
    float4 r = make_float4(acc.x * inv, acc.y * inv, acc.z * inv, acc.w * inv);
    *reinterpret_cast<float4*>(out + (size_t)span * D_DIM + c0) = r;
}

extern "C" void kernel_launch(void* const* d_in, const int* in_sizes, int n_in,
                              void* d_out, int out_size, void* d_ws, size_t ws_size,
                              hipStream_t stream) {
    const float* features = (const float*)d_in[0];
    const int*   begins   = (const int*)d_in[1];
    const int*   ends     = (const int*)d_in[2];
    float*       out      = (float*)d_out;

    const int n_spans = B_DIM * S_DIM;            // 8192
    const int blocks  = n_spans / 4;              // 4 spans (waves) per block
    pooler_kernel<<<blocks, 256, 0, stream>>>(features, begins, ends, out);
}